// Round 3
// baseline (173.740 us; speedup 1.0000x reference)
//
#include <hip/hip_runtime.h>

// RNNAdder round 3b (resubmit — prior round was an infra failure, not a
// kernel failure): transposed recurrence, ONE wave per 16-seq group, zero
// barriers in the main loop. G = h^T:  G_t = tanh(Whh^T G_{t-1} + xp_t^T).
// A single wave holds Whh^T (4 Mtiles x 2 Ktiles), P^T (onehot tables, bias
// folded), Wd^T as resident A-fragments and computes all 64 hidden rows, so
// the per-step D->B relayout is wave-internal: 8x ds_write_b64 + 4x
// ds_read_b128 through an XOR-swizzled scratch (min bank aliasing,
// b128-aligned), pairs packed so reads land directly in B-fragment order
// (no v_perm). Precision: f16 hi + residual*2048 second accumulator.
// Token one-hot staged as 20-bit masks; next-step mask + xp MFMAs prefetched.
// Projection reuses the new Bh frags: 2 MFMAs + one wide store per lane.
// Waves 1-3 of each 256-thr WG only stage P/numpk, then exit. Grid 256 WGs.

typedef _Float16 half8 __attribute__((ext_vector_type(8)));
typedef __fp16 fp16x2 __attribute__((ext_vector_type(2)));
typedef float floatx4 __attribute__((ext_vector_type(4)));
typedef float floatx2 __attribute__((ext_vector_type(2)));
typedef int intx4 __attribute__((ext_vector_type(4)));
typedef int intx2 __attribute__((ext_vector_type(2)));

typedef floatx4 __attribute__((aligned(4))) floatx4_u;
typedef floatx2 __attribute__((aligned(4))) floatx2_u;

#define MFMA16(A, B, C) __builtin_amdgcn_mfma_f32_16x16x32_f16((A), (B), (C), 0, 0, 0)

// LDS dword layout
#define SH_OFF   0                       // [16][32] swizzled h_hi pairs
#define SL_OFF   512                     // [16][32] swizzled h_lo pairs
#define NP_OFF   1024                    // [16][132] token bit-masks
#define P1_OFF   (1024 + 2112)           // [10][68] P1 (bias folded)
#define P2_OFF   (1024 + 2112 + 680)     // [10][68] P2
#define POOL_DW  (1024 + 2112 + 1360)

__global__ __launch_bounds__(256, 1)
void rnn_mfma(const int* __restrict__ num1, const int* __restrict__ num2,
              const float* __restrict__ E, const float* __restrict__ Wxh,
              const float* __restrict__ Whh, const float* __restrict__ bias,
              const float* __restrict__ Wd, const float* __restrict__ bd,
              float* __restrict__ out)
{
    __shared__ __align__(16) int pool[POOL_DW];
    const int tid = threadIdx.x;
    const int g = blockIdx.x;

    float* P1t = (float*)(pool + P1_OFF);
    float* P2t = (float*)(pool + P2_OFF);
    int* numpk = pool + NP_OFF;

    // ---- one-time staging (all 4 waves) ----
    for (int idx = tid; idx < 640; idx += 256) {
        int v = idx >> 6, jj = idx & 63;
        float s1 = bias[jj], s2 = 0.f;
        #pragma unroll
        for (int i = 0; i < 32; ++i) {
            float e = E[v * 32 + i];
            s1 = fmaf(e, Wxh[i * 64 + jj], s1);
            s2 = fmaf(e, Wxh[(32 + i) * 64 + jj], s2);
        }
        P1t[v * 68 + jj] = s1;   // bias folded into P1
        P2t[v * 68 + jj] = s2;
    }
    for (int idx = tid; idx < 2048; idx += 256) {
        int t = idx & 127, m = idx >> 7;
        int s = g * 16 + m;
        numpk[m * 132 + t] = (1 << num1[s * 128 + t]) | (1 << (num2[s * 128 + t] + 10));
    }
    __syncthreads();
    if (tid >= 64) return;          // main loop is single-wave, barrier-free

    const int c = tid & 15;         // sequence-in-group (stays lane&15 in D and B)
    const int q = tid >> 4;
    const int qs = q * 8;

    // ---- resident A-fragments (A layout: m = lane&15, k = q*8+j [+32*kt]) ----
    half8 AW[4][2];                 // Whh^T: AW[mt][kt][j] = Whh[k][16mt+c]
    #pragma unroll
    for (int mt = 0; mt < 4; ++mt)
        #pragma unroll
        for (int kt = 0; kt < 2; ++kt)
            #pragma unroll
            for (int j = 0; j < 8; ++j)
                AW[mt][kt][j] = (_Float16)Whh[(kt * 32 + qs + j) * 64 + mt * 16 + c];

    half8 AP[4];                    // P^T: AP[mt][j] = P[q*8+j][16mt+c]
    #pragma unroll
    for (int mt = 0; mt < 4; ++mt)
        #pragma unroll
        for (int j = 0; j < 8; ++j) {
            int k = qs + j;
            float pv = (k < 10) ? P1t[k * 68 + mt * 16 + c]
                     : (k < 20) ? P2t[(k - 10) * 68 + mt * 16 + c] : 0.f;
            AP[mt][j] = (_Float16)pv;
        }

    half8 AWd[2];                   // Wd^T: AWd[kt][j] = Wd[k*10+c]  (c<10)
    #pragma unroll
    for (int kt = 0; kt < 2; ++kt)
        #pragma unroll
        for (int j = 0; j < 8; ++j)
            AWd[kt][j] = (c < 10) ? (_Float16)Wd[(kt * 32 + qs + j) * 10 + c]
                                  : (_Float16)0.f;

    floatx4 bdv;
    #pragma unroll
    for (int r = 0; r < 4; ++r) {
        int o = q * 4 + r;
        bdv[r] = (o < 10) ? bd[o] : 0.f;
    }

    // ---- loop-invariant LDS scratch addresses (XOR swizzle, b128-aligned) ----
    const int swz = (c & 7) << 2;
    int widx[4], ridx[2];
    #pragma unroll
    for (int mt = 0; mt < 4; ++mt) widx[mt] = c * 32 + ((mt * 8 + q * 2) ^ swz);
    #pragma unroll
    for (int kt = 0; kt < 2; ++kt) ridx[kt] = c * 32 + ((kt * 16 + q * 4) ^ swz);
    const int npb = NP_OFF + c * 132;

    const floatx4 zero4 = {0.f, 0.f, 0.f, 0.f};
    half8 zh;
    #pragma unroll
    for (int j = 0; j < 8; ++j) zh[j] = (_Float16)0.f;

    // one-hot B-fragment from 20-bit mask: B[k=q*8+j][n=c]
    #define BUILD_OH(dst, mask) do {                                          \
        unsigned mq_ = ((unsigned)(mask)) >> qs;                              \
        intx4 v_;                                                             \
        v_.x = ((mq_ & 1u)   ? 0x3C00 : 0) | ((mq_ & 2u)   ? 0x3C000000 : 0); \
        v_.y = ((mq_ & 4u)   ? 0x3C00 : 0) | ((mq_ & 8u)   ? 0x3C000000 : 0); \
        v_.z = ((mq_ & 16u)  ? 0x3C00 : 0) | ((mq_ & 32u)  ? 0x3C000000 : 0); \
        v_.w = ((mq_ & 64u)  ? 0x3C00 : 0) | ((mq_ & 128u) ? 0x3C000000 : 0); \
        dst = __builtin_bit_cast(half8, v_);                                  \
    } while (0)

    // ---- prologue: G_{-1}=0, xp for t=0 ----
    half8 Bh[2], Bl[2];
    Bh[0] = zh; Bh[1] = zh; Bl[0] = zh; Bl[1] = zh;
    half8 Boh;
    BUILD_OH(Boh, pool[npb]);
    floatx4 Cxp[4];
    #pragma unroll
    for (int mt = 0; mt < 4; ++mt) Cxp[mt] = MFMA16(AP[mt], Boh, zero4);

    float* outp = out + ((g * 16 + c) * 128) * 10 + q * 4;

    #pragma unroll 2
    for (int t = 0; t < 128; ++t) {
        int mk_n = pool[npb + ((t + 1) & 127)];   // prefetch next token mask

        // recurrence MFMAs: D_mt = Whh^T G_{t-1} + xp_t ; C2 = residual path
        floatx4 C1[4], C2[4];
        #pragma unroll
        for (int mt = 0; mt < 4; ++mt) C1[mt] = MFMA16(AW[mt][0], Bh[0], Cxp[mt]);
        #pragma unroll
        for (int mt = 0; mt < 4; ++mt) C2[mt] = MFMA16(AW[mt][0], Bl[0], zero4);
        #pragma unroll
        for (int mt = 0; mt < 4; ++mt) C1[mt] = MFMA16(AW[mt][1], Bh[1], C1[mt]);
        #pragma unroll
        for (int mt = 0; mt < 4; ++mt) C2[mt] = MFMA16(AW[mt][1], Bl[1], C2[mt]);

        // tanh + split into (f16 hi, residual*2048 f16), pair-packed writes
        #pragma unroll
        for (int mt = 0; mt < 4; ++mt) {
            float hv[4];
            #pragma unroll
            for (int r = 0; r < 4; ++r) {
                float x  = fmaf(C2[mt][r], (1.f / 2048.f), C1[mt][r]);
                float e2 = __builtin_amdgcn_exp2f(x * 2.885390081777927f);
                hv[r] = 1.f - 2.f * __builtin_amdgcn_rcpf(e2 + 1.f);
            }
            _Float16 h0 = (_Float16)hv[0], h1 = (_Float16)hv[1];
            _Float16 h2 = (_Float16)hv[2], h3 = (_Float16)hv[3];
            intx2 wh;
            wh.x = (int)((unsigned)__builtin_bit_cast(unsigned short, h0)
                 | ((unsigned)__builtin_bit_cast(unsigned short, h1) << 16));
            wh.y = (int)((unsigned)__builtin_bit_cast(unsigned short, h2)
                 | ((unsigned)__builtin_bit_cast(unsigned short, h3) << 16));
            float r0 = (hv[0] - (float)h0) * 2048.f;
            float r1 = (hv[1] - (float)h1) * 2048.f;
            float r2 = (hv[2] - (float)h2) * 2048.f;
            float r3 = (hv[3] - (float)h3) * 2048.f;
            fp16x2 pl0 = __builtin_amdgcn_cvt_pkrtz(r0, r1);
            fp16x2 pl1 = __builtin_amdgcn_cvt_pkrtz(r2, r3);
            intx2 wl;
            wl.x = __builtin_bit_cast(int, pl0);
            wl.y = __builtin_bit_cast(int, pl1);
            *(intx2*)&pool[SH_OFF + widx[mt]] = wh;
            *(intx2*)&pool[SL_OFF + widx[mt]] = wl;
        }

        half8 Boh_n;
        BUILD_OH(Boh_n, mk_n);      // overlaps the DS read latency

        // wave-internal relayout: reads come back already in B-frag order
        intx4 rh0 = *(const intx4*)&pool[SH_OFF + ridx[0]];
        intx4 rh1 = *(const intx4*)&pool[SH_OFF + ridx[1]];
        intx4 rl0 = *(const intx4*)&pool[SL_OFF + ridx[0]];
        intx4 rl1 = *(const intx4*)&pool[SL_OFF + ridx[1]];
        Bh[0] = __builtin_bit_cast(half8, rh0);
        Bh[1] = __builtin_bit_cast(half8, rh1);
        Bl[0] = __builtin_bit_cast(half8, rl0);
        Bl[1] = __builtin_bit_cast(half8, rl1);

        // xp for t+1 (off the critical chain)
        #pragma unroll
        for (int mt = 0; mt < 4; ++mt) Cxp[mt] = MFMA16(AP[mt], Boh_n, zero4);

        // output projection for step t: logits^T = Wd^T G_t (+bd), wide stores
        floatx4 Cp = MFMA16(AWd[0], Bh[0], zero4);
        Cp = MFMA16(AWd[1], Bh[1], Cp);
        if (q < 2) {
            floatx4 st;
            #pragma unroll
            for (int r = 0; r < 4; ++r) st[r] = Cp[r] + bdv[r];
            *(floatx4_u*)outp = st;
        } else if (q == 2) {
            floatx2_u st2 = {Cp[0] + bdv[0], Cp[1] + bdv[1]};
            *(floatx2_u*)outp = st2;
        }
        outp += 10;
    }
    #undef BUILD_OH
}

extern "C" void kernel_launch(void* const* d_in, const int* in_sizes, int n_in,
                              void* d_out, int out_size, void* d_ws, size_t ws_size,
                              hipStream_t stream) {
    const int*   num1 = (const int*)d_in[0];
    const int*   num2 = (const int*)d_in[1];
    const float* E    = (const float*)d_in[2];
    const float* Wxh  = (const float*)d_in[3];
    const float* Whh  = (const float*)d_in[4];
    const float* b    = (const float*)d_in[5];
    const float* Wd   = (const float*)d_in[6];
    const float* bd   = (const float*)d_in[7];
    float* out = (float*)d_out;
    rnn_mfma<<<256, 256, 0, stream>>>(num1, num2, E, Wxh, Whh, b, Wd, bd, out);
}

// Round 5
// 140.207 us; speedup vs baseline: 1.2392x; 1.2392x over previous
//
#include <hip/hip_runtime.h>

// RNNAdder round 4b: verified 4-wave round-2 structure (77us) with
// chain-targeted edits only:
//  (1) one-hot + xp MFMA for step t+1 prefetched during step t (same
//      accumulation order: Cxp = oh*P + 0 first, then += Ah*Wf) — shortens
//      the post-barrier dependent chain to 2 MFMAs and moves the one-hot
//      build off the critical path.
//  (2) output projection runs with a 2-chunk lag (steps t-15..t-8 at
//      t%8==7), which the previous step's barrier already published ->
//      the extra per-8-step __syncthreads (and its vmcnt drain right after
//      the global stores) is gone. Ring depth 8 -> 16 slots.
//  (3) final chunk (steps 120..127) projected in a barrier-free epilogue.
// Everything else (layout, packing, numerics) is bit-identical to round 2.

typedef _Float16 half8 __attribute__((ext_vector_type(8)));
typedef float floatx4 __attribute__((ext_vector_type(4)));
typedef int intx4 __attribute__((ext_vector_type(4)));

#define MFMA16(A, B, C) __builtin_amdgcn_mfma_f32_16x16x32_f16((A), (B), (C), 0, 0, 0)

__global__ __launch_bounds__(256)
void rnn_mfma(const int* __restrict__ num1, const int* __restrict__ num2,
              const float* __restrict__ E, const float* __restrict__ Wxh,
              const float* __restrict__ Whh, const float* __restrict__ bias,
              const float* __restrict__ Wd, const float* __restrict__ bd,
              float* __restrict__ out)
{
    __shared__ __align__(16) int pool[16 * 1088 + 2048]; // h ring (16 slots) + numpk

    int* hist  = pool;               // slot*1088 + m*68 + hid  (packed h dwords)
    int* numpk = pool + 16 * 1088;   // [t][m]

    const int tid  = threadIdx.x;
    const int w    = tid >> 6;       // wave id = N-block
    const int lane = tid & 63;
    const int c    = lane & 15;      // col-in-tile / seq row for A
    const int q    = lane >> 4;      // quad
    const int g    = blockIdx.x;     // sequence group (16 seqs)

    // ---- startup staging (overlaid on hist region) ----
    float* WhhS = (float*)pool;           // 4096 floats
    float* P1t  = (float*)(pool + 4096);  // 640
    float* P2t  = (float*)(pool + 4736);  // 640
    float* WdS  = (float*)(pool + 5376);  // 640
    for (int i = tid; i < 4096; i += 256) WhhS[i] = Whh[i];
    for (int i = tid; i < 640;  i += 256) WdS[i]  = Wd[i];
    for (int idx = tid; idx < 640; idx += 256) {
        int v = idx >> 6, jj = idx & 63;
        float s1 = bias[jj], s2 = 0.f;
        #pragma unroll
        for (int i = 0; i < 32; ++i) {
            float e = E[v * 32 + i];
            s1 = fmaf(e, Wxh[i * 64 + jj], s1);
            s2 = fmaf(e, Wxh[(32 + i) * 64 + jj], s2);
        }
        P1t[idx] = s1;  // bias folded in
        P2t[idx] = s2;
    }
    __syncthreads();

    // ---- gather B-fragments (B[k][n]: n = lane&15, k = q*8 + j + kt*32) ----
    half8 Wf[2], Pf, Wdf[2];
    #pragma unroll
    for (int kt = 0; kt < 2; ++kt)
        #pragma unroll
        for (int j = 0; j < 8; ++j) {
            int k = kt * 32 + q * 8 + j;
            Wf[kt][j]  = (_Float16)WhhS[k * 64 + w * 16 + c];
            Wdf[kt][j] = (c < 10) ? (_Float16)WdS[k * 10 + c] : (_Float16)0.f;
        }
    #pragma unroll
    for (int j = 0; j < 8; ++j) {
        int i = q * 8 + j;
        float pv = (i < 10) ? P1t[i * 64 + w * 16 + c]
                 : (i < 20) ? P2t[(i - 10) * 64 + w * 16 + c] : 0.f;
        Pf[j] = (_Float16)pv;
    }
    float bdv = (c < 10) ? bd[c] : 0.f;
    __syncthreads();   // everyone done reading staging before hist reuse

    // ---- zero slot 15 (h_{-1} = 0), stage token indices ----
    for (int i = tid; i < 1088; i += 256) hist[15 * 1088 + i] = 0;
    for (int it = 0; it < 8; ++it) {
        int idx = it * 256 + tid;
        int m = idx & 15, t = idx >> 4;
        int s = g * 16 + m;
        numpk[t * 16 + m] = num1[s * 128 + t] | (num2[s * 128 + t] << 4);
    }
    __syncthreads();

    const int abase = c * 68 + q * 8;   // A-read dword offset (+slot +kt*32)
    const int wcol  = w * 16 + c;       // write column
    const int ib    = q * 8;
    const floatx4 zero4 = {0.f, 0.f, 0.f, 0.f};

    // ---- prologue: xp for t=0 (Cxp = onehot x P + 0, same order as before) ----
    half8 Aoh0;
    {
        int pk = numpk[0 * 16 + c];
        int v1_ = pk & 15, v2p_ = (pk >> 4) + 10;
        intx4 ohv_;
        ohv_.x = (((ib + 0) == v1_ || (ib + 0) == v2p_) ? 0x3C00u : 0u)
               | ((((ib + 1) == v1_ || (ib + 1) == v2p_) ? 0x3C00u : 0u) << 16);
        ohv_.y = (((ib + 2) == v1_ || (ib + 2) == v2p_) ? 0x3C00u : 0u)
               | ((((ib + 3) == v1_ || (ib + 3) == v2p_) ? 0x3C00u : 0u) << 16);
        ohv_.z = (((ib + 4) == v1_ || (ib + 4) == v2p_) ? 0x3C00u : 0u)
               | ((((ib + 5) == v1_ || (ib + 5) == v2p_) ? 0x3C00u : 0u) << 16);
        ohv_.w = (((ib + 6) == v1_ || (ib + 6) == v2p_) ? 0x3C00u : 0u)
               | ((((ib + 7) == v1_ || (ib + 7) == v2p_) ? 0x3C00u : 0u) << 16);
        Aoh0 = __builtin_bit_cast(half8, ohv_);
    }
    floatx4 Cxp = MFMA16(Aoh0, Pf, zero4);

    #pragma unroll 2
    for (int t = 0; t < 128; ++t) {
        const int sp = ((t + 15) & 15) * 1088;
        const int sc = (t & 15) * 1088;

        // prefetch next token pack early (off-chain)
        int pkn = numpk[((t + 1) & 127) * 16 + c];

        // ---- A fragments: h_hi (lo16) and h_lo (hi16) from packed ring ----
        half8 Ah[2], Al[2];
        #pragma unroll
        for (int kt = 0; kt < 2; ++kt) {
            intx4 ra = *(const intx4*)&hist[sp + abase + kt * 32];
            intx4 rb = *(const intx4*)&hist[sp + abase + kt * 32 + 4];
            intx4 lo, hi;
            lo.x = __builtin_amdgcn_perm(ra.y, ra.x, 0x05040100u);
            lo.y = __builtin_amdgcn_perm(ra.w, ra.z, 0x05040100u);
            lo.z = __builtin_amdgcn_perm(rb.y, rb.x, 0x05040100u);
            lo.w = __builtin_amdgcn_perm(rb.w, rb.z, 0x05040100u);
            hi.x = __builtin_amdgcn_perm(ra.y, ra.x, 0x07060302u);
            hi.y = __builtin_amdgcn_perm(ra.w, ra.z, 0x07060302u);
            hi.z = __builtin_amdgcn_perm(rb.y, rb.x, 0x07060302u);
            hi.w = __builtin_amdgcn_perm(rb.w, rb.z, 0x07060302u);
            Ah[kt] = __builtin_bit_cast(half8, lo);
            Al[kt] = __builtin_bit_cast(half8, hi);
        }

        // ---- recurrence MFMAs (Cxp holds onehot x P from last iteration;
        //      accumulation order identical to round 2) ----
        floatx4 C1 = MFMA16(Ah[0], Wf[0], Cxp);
        C1         = MFMA16(Ah[1], Wf[1], C1);
        floatx4 C2 = MFMA16(Al[0], Wf[0], zero4);
        C2         = MFMA16(Al[1], Wf[1], C2);

        // ---- next step's one-hot + xp MFMA (independent; fills stalls) ----
        {
            int v1_ = pkn & 15, v2p_ = (pkn >> 4) + 10;
            intx4 ohv_;
            ohv_.x = (((ib + 0) == v1_ || (ib + 0) == v2p_) ? 0x3C00u : 0u)
                   | ((((ib + 1) == v1_ || (ib + 1) == v2p_) ? 0x3C00u : 0u) << 16);
            ohv_.y = (((ib + 2) == v1_ || (ib + 2) == v2p_) ? 0x3C00u : 0u)
                   | ((((ib + 3) == v1_ || (ib + 3) == v2p_) ? 0x3C00u : 0u) << 16);
            ohv_.z = (((ib + 4) == v1_ || (ib + 4) == v2p_) ? 0x3C00u : 0u)
                   | ((((ib + 5) == v1_ || (ib + 5) == v2p_) ? 0x3C00u : 0u) << 16);
            ohv_.w = (((ib + 6) == v1_ || (ib + 6) == v2p_) ? 0x3C00u : 0u)
                   | ((((ib + 7) == v1_ || (ib + 7) == v2p_) ? 0x3C00u : 0u) << 16);
            half8 Aohn = __builtin_bit_cast(half8, ohv_);
            Cxp = MFMA16(Aohn, Pf, zero4);
        }

        // ---- tanh + pack (hi f16 | residual*2048 f16) + ring write ----
        #pragma unroll
        for (int r = 0; r < 4; ++r) {
            float x  = C1[r] + C2[r] * (1.f / 2048.f);
            float e2 = __builtin_amdgcn_exp2f(x * 2.885390081777927f);
            float hv = 1.f - 2.f * __builtin_amdgcn_rcpf(e2 + 1.f);
            _Float16 hh = (_Float16)hv;
            float hif = (float)hh;
            _Float16 hl = (_Float16)((hv - hif) * 2048.f);
            unsigned phi = (unsigned)__builtin_bit_cast(unsigned short, hh);
            unsigned plo = (unsigned)__builtin_bit_cast(unsigned short, hl);
            hist[sc + (q * 4 + r) * 68 + wcol] = (int)(phi | (plo << 16));
        }

        // ---- output projection, 2-chunk lag: steps t-15..t-8 (published by
        //      the previous step's barrier — NO extra barrier needed) ----
        if ((t & 7) == 7 && t >= 15) {
            int tb = t - 15;
            #pragma unroll
            for (int u = 0; u < 2; ++u) {
                int tt = 2 * w + u;
                int sl = ((tb + tt) & 15) * 1088;
                half8 Ph[2];
                #pragma unroll
                for (int kt = 0; kt < 2; ++kt) {
                    intx4 ra = *(const intx4*)&hist[sl + abase + kt * 32];
                    intx4 rb = *(const intx4*)&hist[sl + abase + kt * 32 + 4];
                    intx4 lo;
                    lo.x = __builtin_amdgcn_perm(ra.y, ra.x, 0x05040100u);
                    lo.y = __builtin_amdgcn_perm(ra.w, ra.z, 0x05040100u);
                    lo.z = __builtin_amdgcn_perm(rb.y, rb.x, 0x05040100u);
                    lo.w = __builtin_amdgcn_perm(rb.w, rb.z, 0x05040100u);
                    Ph[kt] = __builtin_bit_cast(half8, lo);
                }
                floatx4 Cp = MFMA16(Ph[0], Wdf[0], zero4);
                Cp         = MFMA16(Ph[1], Wdf[1], Cp);
                int tg = tb + tt;
                if (c < 10) {
                    #pragma unroll
                    for (int r = 0; r < 4; ++r) {
                        int m = q * 4 + r;
                        out[((g * 16 + m) * 128 + tg) * 10 + c] = Cp[r] + bdv;
                    }
                }
            }
        }

        __syncthreads();   // publish this step's h before next step reads
    }

    // ---- epilogue: final chunk (steps 120..127), published by last barrier ----
    {
        int tb = 120;
        #pragma unroll
        for (int u = 0; u < 2; ++u) {
            int tt = 2 * w + u;
            int sl = ((tb + tt) & 15) * 1088;
            half8 Ph[2];
            #pragma unroll
            for (int kt = 0; kt < 2; ++kt) {
                intx4 ra = *(const intx4*)&hist[sl + abase + kt * 32];
                intx4 rb = *(const intx4*)&hist[sl + abase + kt * 32 + 4];
                intx4 lo;
                lo.x = __builtin_amdgcn_perm(ra.y, ra.x, 0x05040100u);
                lo.y = __builtin_amdgcn_perm(ra.w, ra.z, 0x05040100u);
                lo.z = __builtin_amdgcn_perm(rb.y, rb.x, 0x05040100u);
                lo.w = __builtin_amdgcn_perm(rb.w, rb.z, 0x05040100u);
                Ph[kt] = __builtin_bit_cast(half8, lo);
            }
            floatx4 Cp = MFMA16(Ph[0], Wdf[0], zero4);
            Cp         = MFMA16(Ph[1], Wdf[1], Cp);
            int tg = tb + tt;
            if (c < 10) {
                #pragma unroll
                for (int r = 0; r < 4; ++r) {
                    int m = q * 4 + r;
                    out[((g * 16 + m) * 128 + tg) * 10 + c] = Cp[r] + bdv;
                }
            }
        }
    }
}

extern "C" void kernel_launch(void* const* d_in, const int* in_sizes, int n_in,
                              void* d_out, int out_size, void* d_ws, size_t ws_size,
                              hipStream_t stream) {
    const int*   num1 = (const int*)d_in[0];
    const int*   num2 = (const int*)d_in[1];
    const float* E    = (const float*)d_in[2];
    const float* Wxh  = (const float*)d_in[3];
    const float* Whh  = (const float*)d_in[4];
    const float* b    = (const float*)d_in[5];
    const float* Wd   = (const float*)d_in[6];
    const float* bd   = (const float*)d_in[7];
    float* out = (float*)d_out;
    rnn_mfma<<<256, 256, 0, stream>>>(num1, num2, E, Wxh, Whh, b, Wd, bd, out);
}

// Round 6
// 121.843 us; speedup vs baseline: 1.4259x; 1.1507x over previous
//
#include <hip/hip_runtime.h>

// RNNAdder round 5: 4-wave round-2 structure, issue-count attack.
//  (a) h stored as SEPARATE hi/lo f16 arrays, row stride 72 f16 (144B pad ->
//      bank-uniform b128 reads): A-frags are direct ds_read_b128, zero v_perm.
//  (b) one-hot A-frag via 256-entry LDS LUT (built once): 2 VALU + 1 b128
//      read replace ~40 compare/select ops per step.
//  (c) step loop unrolled 16 (ring = 16 slots): all LDS addresses are
//      invariant VGPR + imm offset; raw s_barrier with lgkmcnt-only wait so
//      projection global stores never drain at barriers; projection stores
//      are base-pointer + imm.
// Numerics bit-identical to round 4b (same op kinds/order on value path):
// f16-hi + residual*2048 dual accumulator, Cxp prefetched one step ahead.

typedef _Float16 half8 __attribute__((ext_vector_type(8)));
typedef float floatx4 __attribute__((ext_vector_type(4)));

#define MFMA16(A, B, C) __builtin_amdgcn_mfma_f32_16x16x32_f16((A), (B), (C), 0, 0, 0)
#define BARRIER() asm volatile("s_waitcnt lgkmcnt(0)\n\ts_barrier" ::: "memory")

// dword offsets in pool
#define HI_DW   0                  // 16 slots x 16 rows x 36 dw (72 f16/row)
#define LO_DW   9216               // 2 slots x 576 dw
#define LUT_DW  10368              // 256 entries x 4 dw
#define NP_DW   11392              // 130 rows x 16 (rows 128-129 = pad)
#define POOL_DW 13472
#define LO_E    (LO_DW * 2)        // f16-element offset of lo array

__global__ __launch_bounds__(256)
void rnn_mfma(const int* __restrict__ num1, const int* __restrict__ num2,
              const float* __restrict__ E, const float* __restrict__ Wxh,
              const float* __restrict__ Whh, const float* __restrict__ bias,
              const float* __restrict__ Wd, const float* __restrict__ bd,
              float* __restrict__ out)
{
    __shared__ __align__(16) int pool[POOL_DW];
    _Float16* hiF  = (_Float16*)pool;
    int*      lutI = pool + LUT_DW;
    int*      numpk = pool + NP_DW;

    const int tid  = threadIdx.x;
    const int w    = tid >> 6;       // wave id = hidden N-block
    const int lane = tid & 63;
    const int c    = lane & 15;
    const int q    = lane >> 4;
    const int g    = blockIdx.x;     // 16-sequence group

    // ---- startup staging (overlaid on hi-ring region, dwords 0..6015) ----
    float* WhhS = (float*)pool;           // 4096
    float* P1t  = (float*)(pool + 4096);  // 640
    float* P2t  = (float*)(pool + 4736);  // 640
    float* WdS  = (float*)(pool + 5376);  // 640
    for (int i = tid; i < 4096; i += 256) WhhS[i] = Whh[i];
    for (int i = tid; i < 640;  i += 256) WdS[i]  = Wd[i];
    for (int idx = tid; idx < 640; idx += 256) {
        int v = idx >> 6, jj = idx & 63;
        float s1 = bias[jj], s2 = 0.f;
        #pragma unroll
        for (int i = 0; i < 32; ++i) {
            float e = E[v * 32 + i];
            s1 = fmaf(e, Wxh[i * 64 + jj], s1);
            s2 = fmaf(e, Wxh[(32 + i) * 64 + jj], s2);
        }
        P1t[idx] = s1;  // bias folded in
        P2t[idx] = s2;
    }
    // one-hot LUT: entry e, dword j holds f16(1.0) in low/high half per bits 2j,2j+1
    {
        int e = tid;  // 256 threads = 256 entries
        #pragma unroll
        for (int j = 0; j < 4; ++j)
            lutI[e * 4 + j] = (((e >> (2 * j)) & 1) ? 0x3C00 : 0)
                            | (((e >> (2 * j + 1)) & 1) ? 0x3C000000 : 0);
    }
    // token bit-masks: bit v1 | bit (v2+10)
    for (int it = 0; it < 8; ++it) {
        int idx = it * 256 + tid;
        int m = idx & 15, t = idx >> 4;
        int s = g * 16 + m;
        numpk[t * 16 + m] = (1 << num1[s * 128 + t]) | (1 << (num2[s * 128 + t] + 10));
    }
    // zero ring slots used by t=0: hi slot 15, lo slot 1
    for (int i = tid; i < 576; i += 256) {
        pool[15 * 576 + i]     = 0;
        pool[LO_DW + 576 + i]  = 0;
    }
    __syncthreads();

    // ---- B-fragments (B[k][n]: n = c, k = q*8 + j + kt*32) ----
    half8 Wf[2], Pf, Wdf[2];
    #pragma unroll
    for (int kt = 0; kt < 2; ++kt)
        #pragma unroll
        for (int j = 0; j < 8; ++j) {
            int k = kt * 32 + q * 8 + j;
            Wf[kt][j]  = (_Float16)WhhS[k * 64 + w * 16 + c];
            Wdf[kt][j] = (c < 10) ? (_Float16)WdS[k * 10 + c] : (_Float16)0.f;
        }
    #pragma unroll
    for (int j = 0; j < 8; ++j) {
        int i2 = q * 8 + j;
        float pv = (i2 < 10) ? P1t[i2 * 64 + w * 16 + c]
                 : (i2 < 20) ? P2t[(i2 - 10) * 64 + w * 16 + c] : 0.f;
        Pf[j] = (_Float16)pv;
    }
    float bdv = (c < 10) ? bd[c] : 0.f;
    __syncthreads();   // staging region free for ring reuse after this

    // ---- loop-invariant addresses (f16-element units) ----
    const int rvE = c * 72 + q * 8;              // A-read: row c, k-base q*8
    const int wvE = (q * 4) * 72 + w * 16 + c;   // write: row q*4(+r), col w*16+c
    int pvE[2];                                  // projection read bases (tt = 2w+u)
    pvE[0] = rvE + (2 * w + 0) * 1152;
    pvE[1] = rvE + (2 * w + 1) * 1152;

    float* outP[2][4];
    #pragma unroll
    for (int u = 0; u < 2; ++u)
        #pragma unroll
        for (int r = 0; r < 4; ++r)
            outP[u][r] = out + (((g * 16 + q * 4 + r) * 128) + 2 * w + u) * 10 + c;

    const floatx4 zero4 = {0.f, 0.f, 0.f, 0.f};

    // ---- prologue: Cxp for t=0 ----
    floatx4 Cxp;
    {
        int mk = numpk[c];
        int mq = (mk >> (q * 8)) & 0xFF;
        half8 Aoh = *(const half8*)&lutI[mq * 4];
        Cxp = MFMA16(Aoh, Pf, zero4);
    }

    for (int tb = 0; tb < 128; tb += 16) {
        #pragma unroll
        for (int i = 0; i < 16; ++i) {
            // next-step token mask (off-chain prefetch; row tb+i+1 <= 128, padded)
            int mk = numpk[(tb + i + 1) * 16 + c];

            // A-frags: direct b128 reads, no perms
            const int sp = (i + 15) & 15;
            half8 Ah0 = *(const half8*)&hiF[sp * 1152 + rvE];
            half8 Ah1 = *(const half8*)&hiF[sp * 1152 + rvE + 32];
            half8 Al0 = *(const half8*)&hiF[LO_E + ((i + 1) & 1) * 1152 + rvE];
            half8 Al1 = *(const half8*)&hiF[LO_E + ((i + 1) & 1) * 1152 + rvE + 32];

            // recurrence (same accumulation order as round 4b)
            floatx4 C1 = MFMA16(Ah0, Wf[0], Cxp);
            C1         = MFMA16(Ah1, Wf[1], C1);
            floatx4 C2 = MFMA16(Al0, Wf[0], zero4);
            C2         = MFMA16(Al1, Wf[1], C2);

            // next step's one-hot via LUT + xp MFMA (independent, fills stalls)
            int mq = (mk >> (q * 8)) & 0xFF;
            half8 Aoh = *(const half8*)&lutI[mq * 4];
            Cxp = MFMA16(Aoh, Pf, zero4);

            // tanh + hi/lo split, b16 writes (value path identical to round 4b)
            #pragma unroll
            for (int r = 0; r < 4; ++r) {
                float x  = C1[r] + C2[r] * (1.f / 2048.f);
                float e2 = __builtin_amdgcn_exp2f(x * 2.885390081777927f);
                float hv = 1.f - 2.f * __builtin_amdgcn_rcpf(e2 + 1.f);
                _Float16 hh = (_Float16)hv;
                float hif = (float)hh;
                _Float16 hl = (_Float16)((hv - hif) * 2048.f);
                hiF[i * 1152 + wvE + r * 72] = hh;
                hiF[LO_E + (i & 1) * 1152 + wvE + r * 72] = hl;
            }

            // projection: at i==7 project prev block's steps (slots 8..15,
            // tg offset -8); at i==15 project this block's steps 0..7 (slots
            // 0..7, tg offset 0). All slots published by earlier barriers.
            if ((i == 7 && tb != 0) || i == 15) {
                const int sb = (i == 7) ? 8 : 0;     // slot base (imm)
                const int od = (i == 7) ? -80 : 0;   // f32 offset = -8 steps
                #pragma unroll
                for (int u = 0; u < 2; ++u) {
                    half8 p0 = *(const half8*)&hiF[pvE[u] + sb * 1152];
                    half8 p1 = *(const half8*)&hiF[pvE[u] + sb * 1152 + 32];
                    floatx4 Cp = MFMA16(p0, Wdf[0], zero4);
                    Cp         = MFMA16(p1, Wdf[1], Cp);
                    if (c < 10) {
                        #pragma unroll
                        for (int r = 0; r < 4; ++r)
                            outP[u][r][od] = Cp[r] + bdv;
                    }
                }
            }

            BARRIER();   // lgkmcnt-only: global stores stay in flight
        }
        #pragma unroll
        for (int u = 0; u < 2; ++u)
            #pragma unroll
            for (int r = 0; r < 4; ++r)
                outP[u][r] += 160;   // +16 steps
    }

    // ---- epilogue: steps 120..127 (slots 8..15); outP sits at tg = 128+tt ----
    #pragma unroll
    for (int u = 0; u < 2; ++u) {
        half8 p0 = *(const half8*)&hiF[pvE[u] + 8 * 1152];
        half8 p1 = *(const half8*)&hiF[pvE[u] + 8 * 1152 + 32];
        floatx4 Cp = MFMA16(p0, Wdf[0], zero4);
        Cp         = MFMA16(p1, Wdf[1], Cp);
        if (c < 10) {
            #pragma unroll
            for (int r = 0; r < 4; ++r)
                outP[u][r][-80] = Cp[r] + bdv;
        }
    }
}

extern "C" void kernel_launch(void* const* d_in, const int* in_sizes, int n_in,
                              void* d_out, int out_size, void* d_ws, size_t ws_size,
                              hipStream_t stream) {
    const int*   num1 = (const int*)d_in[0];
    const int*   num2 = (const int*)d_in[1];
    const float* E    = (const float*)d_in[2];
    const float* Wxh  = (const float*)d_in[3];
    const float* Whh  = (const float*)d_in[4];
    const float* b    = (const float*)d_in[5];
    const float* Wd   = (const float*)d_in[6];
    const float* bd   = (const float*)d_in[7];
    float* out = (float*)d_out;
    rnn_mfma<<<256, 256, 0, stream>>>(num1, num2, E, Wxh, Whh, b, Wd, bd, out);
}